// Round 9
// baseline (355.286 us; speedup 1.0000x reference)
//
#include <hip/hip_runtime.h>
#include <stdint.h>

typedef unsigned short u16;
typedef unsigned int   u32;
typedef int v4i __attribute__((ext_vector_type(4)));

static constexpr int Bd = 4096;   // batch
static constexpr int Kd = 2048;   // in-features (GEMM K)
static constexpr int Fd = 4096;   // out-features

// Workspace (bytes). yr aliases X1B+W1B (dead before GEMM writes).
static constexpr size_t OFF_QX   = 0;          // i8 [4096*2048]              (8 MB)
static constexpr size_t OFF_QWT  = 8388608;    // i8 [4096*2048] transposed   (8 MB)
static constexpr size_t OFF_X1B  = 16777216;   // u16[4096*2048] bf16         (16 MB)
static constexpr size_t OFF_W1B  = 33554432;   // u32[2048*2048] bf16 pairs   (16 MB)
static constexpr size_t OFF_YR   = 16777216;   // u16[4096*4096] aliases X1B/W1B (32 MB)
static constexpr size_t OFF_SCAL = 83886080;   // 2x u32 (max|X1|, max|W1| float bits)

// ---------------- FWHT helpers ----------------
__device__ __forceinline__ void fwht16(float* v) {
#pragma unroll
  for (int b = 1; b < 16; b <<= 1) {
#pragma unroll
    for (int i = 0; i < 16; ++i) {
      if (!(i & b)) { float a = v[i]; float c = v[i | b]; v[i] = a + c; v[i | b] = a - c; }
    }
  }
}
__device__ __forceinline__ void fwht64(float* v) {
#pragma unroll
  for (int b = 1; b < 64; b <<= 1) {
#pragma unroll
    for (int i = 0; i < 64; ++i) {
      if (!(i & b)) { float a = v[i]; float c = v[i | b]; v[i] = a + c; v[i | b] = a - c; }
    }
  }
}

// ---------------- bf16 pack/unpack ----------------
__device__ __forceinline__ void unpack2(u32 u, float& a, float& b) {
  a = __uint_as_float(u << 16);
  b = __uint_as_float(u & 0xffff0000u);
}
__device__ __forceinline__ float bf16_f32(u16 h) {
  return __uint_as_float(((u32)h) << 16);
}
__device__ __forceinline__ u16 bf16_rne(float f) {
  u32 x = __float_as_uint(f);
  return (u16)(((x + 0x7fffu + ((x >> 16) & 1u)) >> 16) & 0xffffu);
}
__device__ __forceinline__ u32 pack2(float a, float b) {
  u32 x = __float_as_uint(a), y = __float_as_uint(b);
  u32 lo = ((x + 0x7fffu + ((x >> 16) & 1u)) >> 16) & 0xffffu;
  u32 hi = (y + 0x7fffu + ((y >> 16) & 1u)) & 0xffff0000u;
  return lo | hi;
}

// ---- x-path stage 1: H64 on consecutive 64-row groups, f32 -> bf16 (u16/col) ----
// G13: float4 global loads (16B/lane) into an LDS half-tile, column reads from
// LDS. Layout: float4 slots [32 rows][64+1 pad] -> b128 writes conflict-free,
// f32 column reads lane-consecutive. FP order per column unchanged.
__global__ __launch_bounds__(256) void xcol_s1(const float* __restrict__ x,
                                               u16* __restrict__ X1h,
                                               u32* __restrict__ scal) {
  if (blockIdx.x == 0 && blockIdx.y == 0 && threadIdx.x < 2) scal[threadIdx.x] = 0u;
  __shared__ float4 st4[32 * 65];
  float* stf = (float*)st4;
  const int t = threadIdx.x;
  const int c0 = blockIdx.x * 256;           // col chunk base (grid.x = 8)
  const int base = blockIdx.y * 64;
  const int w = t >> 6, c4 = t & 63;
  float v[64];
#pragma unroll
  for (int h = 0; h < 2; ++h) {
    if (h) __syncthreads();                  // st4 reads (h=0) done before overwrite
#pragma unroll
    for (int i = 0; i < 8; ++i) {
      int r = 4 * i + w;                     // 0..31, wave-uniform
      st4[r * 65 + c4] =
          *(const float4*)(x + (size_t)(base + h * 32 + r) * 2048 + c0 + c4 * 4);
    }
    __syncthreads();
#pragma unroll
    for (int r = 0; r < 32; ++r) v[h * 32 + r] = stf[r * 260 + t];
  }
  fwht64(v);
  const int c = c0 + t;
#pragma unroll
  for (int r = 0; r < 64; ++r)
    X1h[(size_t)(base + r) * 2048 + c] = bf16_rne(v[r]);
}

// ---- x-path stage 2: H64 on stride-64 rows, in-place bf16, + max ----
// LDS-staged loads (G13): 64 strided rows x 256 cols tile, uint4 global reads.
__global__ __launch_bounds__(256) void xcol_s2(u16* __restrict__ X1h,
                                               u32* __restrict__ gmax) {
  __shared__ u16 tile[64 * 264];   // row stride 264 u16 (+8 pad) -> spread banks
  __shared__ float red[4];
  const int t = threadIdx.x;
  const int c0 = blockIdx.x * 256;           // col chunk base (grid.x = 8)
  const int base = blockIdx.y;               // 0..63
#pragma unroll
  for (int i = 0; i < 8; ++i) {
    int idx = t + 256 * i;                   // 0..2047
    int r = idx >> 5, u = idx & 31;
    uint4 d = *(const uint4*)(X1h + (size_t)(base + r * 64) * 2048 + c0 + u * 8);
    *(uint4*)(&tile[r * 264 + u * 8]) = d;
  }
  __syncthreads();
  float v[64];
#pragma unroll
  for (int r = 0; r < 64; ++r) v[r] = bf16_f32(tile[r * 264 + t]);
  fwht64(v);
  float m = 0.f;
  const int c = c0 + t;
#pragma unroll
  for (int r = 0; r < 64; ++r) {
    X1h[(size_t)(base + r * 64) * 2048 + c] = bf16_rne(v[r]);
    m = fmaxf(m, fabsf(v[r]));
  }
#pragma unroll
  for (int off = 32; off > 0; off >>= 1) m = fmaxf(m, __shfl_down(m, off));
  if ((t & 63) == 0) red[t >> 6] = m;
  __syncthreads();
  if (t == 0) {
    m = fmaxf(fmaxf(red[0], red[1]), fmaxf(red[2], red[3]));
    atomicMax(gmax, __float_as_uint(m));
  }
}

// ---------------- w-path: full FWHT-4096 per row, f32 in -> bf16 out, + max --------
// G13: stage the row via float4 loads (16B/lane) into the padded LDS layout,
// then the original strided phase-C read proceeds from LDS. FP order unchanged.
__global__ __launch_bounds__(256) void roww_fwht(const float* __restrict__ in,
                                                 u32* __restrict__ W1b,
                                                 u32* __restrict__ gmax) {
  __shared__ float s[4224];
  __shared__ float red[4];
  const int t = threadIdx.x;
  const size_t rowoff = (size_t)blockIdx.x * 4096;
  float v[16];
  // stage: 1024 float4 slots, slot = t + 256*i (1KB contiguous per wave-inst)
#pragma unroll
  for (int i = 0; i < 4; ++i) {
    int sl = t + 256 * i;
    float4 d = *(const float4*)(in + rowoff + sl * 4);
    int ep = sl * 4 + ((sl * 4) >> 5);       // (e+j)>>5 == e>>5 for j<4 here
    s[ep + 0] = d.x; s[ep + 1] = d.y; s[ep + 2] = d.z; s[ep + 3] = d.w;
  }
  __syncthreads();
#pragma unroll
  for (int j = 0; j < 16; ++j) { int e = (j << 8) | t; v[j] = s[e + (e >> 5)]; }
  fwht16(v);
#pragma unroll
  for (int j = 0; j < 16; ++j) { int e = (j << 8) | t; s[e + (e >> 5)] = v[j]; }
  __syncthreads();
#pragma unroll
  for (int j = 0; j < 16; ++j) { int e = ((t >> 4) << 8) | (j << 4) | (t & 15); v[j] = s[e + (e >> 5)]; }
  fwht16(v);
#pragma unroll
  for (int j = 0; j < 16; ++j) { int e = ((t >> 4) << 8) | (j << 4) | (t & 15); s[e + (e >> 5)] = v[j]; }
  __syncthreads();
#pragma unroll
  for (int j = 0; j < 16; ++j) { int e = (t << 4) | j; v[j] = s[e + (e >> 5)]; }
  fwht16(v);
  // store as bf16 pairs: cols t*16 .. t*16+15
  uint4 o0, o1;
  o0.x = pack2(v[0], v[1]);   o0.y = pack2(v[2], v[3]);
  o0.z = pack2(v[4], v[5]);   o0.w = pack2(v[6], v[7]);
  o1.x = pack2(v[8], v[9]);   o1.y = pack2(v[10], v[11]);
  o1.z = pack2(v[12], v[13]); o1.w = pack2(v[14], v[15]);
  uint4* op = (uint4*)(W1b + (size_t)blockIdx.x * 2048 + t * 8);
  op[0] = o0; op[1] = o1;
  float m = 0.f;
#pragma unroll
  for (int j = 0; j < 16; ++j) m = fmaxf(m, fabsf(v[j]));
#pragma unroll
  for (int off = 32; off > 0; off >>= 1) m = fmaxf(m, __shfl_down(m, off));
  if ((t & 63) == 0) red[t >> 6] = m;
  __syncthreads();
  if (t == 0) {
    m = fmaxf(fmaxf(red[0], red[1]), fmaxf(red[2], red[3]));
    atomicMax(gmax, __float_as_uint(m));
  }
}

// ---------------- Stochastic quantization ----------------
__device__ __forceinline__ float quant1(float X1, float nz, float s) {
  float xr = X1 * 0.015625f;         // /64, exact
  float xs = xr / s;
  float f  = floorf(xs);
  float q  = f + ((nz < (xs - f)) ? 1.0f : 0.0f);
  return fminf(fmaxf(q, -127.0f), 127.0f);
}
__device__ __forceinline__ u32 pk4(float a, float b, float c, float d) {
  return ((u32)(unsigned char)(char)(int)a)        |
         (((u32)(unsigned char)(char)(int)b) << 8) |
         (((u32)(unsigned char)(char)(int)c) << 16)|
         (((u32)(unsigned char)(char)(int)d) << 24);
}

__global__ __launch_bounds__(256) void quant_x_i8(const uint4* __restrict__ X1b,
                                                  const float4* __restrict__ nz,
                                                  uint2* __restrict__ qx,
                                                  const u32* __restrict__ scal) {
  size_t g = (size_t)blockIdx.x * 256 + threadIdx.x;
  float s = (__uint_as_float(scal[0]) * 0.015625f) / 127.0f;
  uint4 xv = X1b[g];
  float4 na = nz[2 * g], nb = nz[2 * g + 1];
  float a, b, c, d, e, f, gg, h;
  unpack2(xv.x, a, b);  unpack2(xv.y, c, d);
  unpack2(xv.z, e, f);  unpack2(xv.w, gg, h);
  u32 lo = pk4(quant1(a, na.x, s), quant1(b, na.y, s), quant1(c, na.z, s), quant1(d, na.w, s));
  u32 hi = pk4(quant1(e, nb.x, s), quant1(f, nb.y, s), quant1(gg, nb.z, s), quant1(h, nb.w, s));
  qx[g] = make_uint2(lo, hi);
}

// Quantize W1b [K,F] (bf16 pairs) and write transposed i8 [F,K].
__global__ __launch_bounds__(256) void quant_w_t_i8(const u32* __restrict__ W1b,
                                                    const float2* __restrict__ nz,
                                                    char* __restrict__ qwT,
                                                    const u32* __restrict__ scal) {
  __shared__ float tile[64][65];
  const int t = threadIdx.x;
  const int k0 = blockIdx.x * 64;   // over K=2048
  const int n0 = blockIdx.y * 64;   // over F=4096
  float s = (__uint_as_float(scal[1]) * 0.015625f) / 127.0f;
#pragma unroll
  for (int i = 0; i < 8; ++i) {
    int idx = t + 256 * i;          // 0..2047 over (k, np)
    int k = idx >> 5, np = idx & 31;
    u32 u = W1b[(size_t)(k0 + k) * 2048 + (n0 >> 1) + np];
    float2 nv = nz[(size_t)(k0 + k) * 2048 + (n0 >> 1) + np];
    float a, b; unpack2(u, a, b);
    tile[k][2 * np]     = quant1(a, nv.x, s);
    tile[k][2 * np + 1] = quant1(b, nv.y, s);
  }
  __syncthreads();
  const int kq = t & 15, nb = t >> 4;
#pragma unroll
  for (int i = 0; i < 4; ++i) {
    int n = nb + 16 * i;
    u32 p = pk4(tile[4 * kq + 0][n], tile[4 * kq + 1][n],
                tile[4 * kq + 2][n], tile[4 * kq + 3][n]);
    *(u32*)(qwT + (size_t)(n0 + n) * Kd + k0 + 4 * kq) = p;
  }
}

// ---------------- GEMM (i8 MFMA) + fused Rl/Cl output-rotation epilogue -------------
// 128^2 tile + 2-phase LDS double-buffer (R7: 65 us, verified), GM=8 panel
// swizzle. R8's XCD-region swizzle halved FETCH (69.7->32.9 MB) but ran 88 us
// (same busy cycles, +23 us idle) -- mechanism unproven (possibly the R6-class
// environmental variance) -> reverted to the verified mapping. If GM=8 also
// lands ~88 this run, R8's regression was noise and the low-traffic swizzle
// deserves a re-test.
__device__ __forceinline__ void async16(const void* g, void* l) {
  __builtin_amdgcn_global_load_lds((__attribute__((address_space(1))) void*)(g),
                                   (__attribute__((address_space(3))) void*)(l),
                                   16, 0, 0);
}

__global__ __launch_bounds__(256) void gemm_i8(const char* __restrict__ A,   // [4096,2048] i8
                                               const char* __restrict__ Bt,  // [4096,2048] i8
                                               u16* __restrict__ C,          // [4096,4096] bf16
                                               const u32* __restrict__ scal) {
  __shared__ __align__(16) char As[2][128 * 128];
  __shared__ __align__(16) char Bs[2][128 * 128];
  const int t = threadIdx.x;
  const int w = t >> 6, l = t & 63;
  const int l15 = l & 15, quad = l >> 4;
  const int xorr = l15 & 7;
  // gm=8 panel swizzle for L2 locality (grid = 1024 1D)
  const int GM = 8, NN = 32, grp = GM * NN;
  int pid = blockIdx.x;
  int gid = pid / grp;
  int mm = gid * GM + (pid % GM);
  int nn = (pid % grp) / GM;
  const int m0 = mm * 128, n0 = nn * 128;
  const int mw = (w & 1) * 64, nw = (w >> 1) * 64;
  v4i acc[4][4] = {};

  // XOR source swizzle so LDS ds_read_b128 spreads over banks (0 conflicts)
  const int srow_lo = l >> 3;
  const int sbg = (l & 7) ^ ((l >> 3) & 7);

  // per-thread staging addresses (row/col within tile are kt-invariant)
  const int srow = (w * 4) * 8 + srow_lo;     // rows srow, srow+8, +16, +24
  const char* ga = A  + (size_t)(m0 + srow) * Kd + sbg * 16;
  const char* gb = Bt + (size_t)(n0 + srow) * Kd + sbg * 16;

  // prologue: stage K-tile 0 into buffer 0
#pragma unroll
  for (int i = 0; i < 4; ++i) {
    async16(ga + (size_t)(i * 8) * Kd, As[0] + (w * 4 + i) * 1024);
    async16(gb + (size_t)(i * 8) * Kd, Bs[0] + (w * 4 + i) * 1024);
  }
  __syncthreads();   // drains vmcnt(0): tile 0 resident

#pragma unroll 2
  for (int kt = 0; kt < 16; ++kt) {
    const char* curA = As[kt & 1];
    const char* curB = Bs[kt & 1];
    // issue next-tile staging into the alternate buffer (flies under compute)
    if (kt + 1 < 16) {
      char* nxtA = (char*)As[(kt + 1) & 1];
      char* nxtB = (char*)Bs[(kt + 1) & 1];
      const size_t kg = (size_t)(kt + 1) * 128;
#pragma unroll
      for (int i = 0; i < 4; ++i) {
        async16(ga + (size_t)(i * 8) * Kd + kg, nxtA + (w * 4 + i) * 1024);
        async16(gb + (size_t)(i * 8) * Kd + kg, nxtB + (w * 4 + i) * 1024);
      }
      __builtin_amdgcn_sched_barrier(0);   // pin: loads issued before compute
    }
#pragma unroll
    for (int kc = 0; kc < 2; ++kc) {
      v4i av[4], bv[4];
#pragma unroll
      for (int mi = 0; mi < 4; ++mi) {
        int row = mw + mi * 16 + l15;
        av[mi] = *(const v4i*)(curA + row * 128 + (((kc * 4 + quad) ^ xorr) * 16));
      }
#pragma unroll
      for (int ni = 0; ni < 4; ++ni) {
        int row = nw + ni * 16 + l15;
        bv[ni] = *(const v4i*)(curB + row * 128 + (((kc * 4 + quad) ^ xorr) * 16));
      }
#pragma unroll
      for (int mi = 0; mi < 4; ++mi)
#pragma unroll
        for (int ni = 0; ni < 4; ++ni)
          acc[mi][ni] = __builtin_amdgcn_mfma_i32_16x16x64_i8(av[mi], bv[ni], acc[mi][ni], 0, 0, 0);
    }
    // one barrier per tile: built-in vmcnt(0) waits only the residual latency
    // not covered by the compute above; also WAR-protects the buffer swap.
    __syncthreads();
  }
  float sx = (__uint_as_float(scal[0]) * 0.015625f) / 127.0f;
  float sw = (__uint_as_float(scal[1]) * 0.015625f) / 127.0f;
  float alpha = sx * sw * (1.0f / 4096.0f);

  // ---- fused epilogue: H64 over row-low bits (Rl) and col-low bits (Cl) ----
  // Wave quadrant = aligned 64x64 tile. row6 = mi*16+quad*4+r, col6 = ni*16+l15.
  // Register-resident bits {r, ni, mi} -> plain fwht64 over flat idx (order-free).
  // Lane-resident bits {l15: lane 0-3, quad: lane 4-5} -> 6 shfl_xor butterflies.
  float vals[64];
#pragma unroll
  for (int mi = 0; mi < 4; ++mi)
#pragma unroll
    for (int ni = 0; ni < 4; ++ni)
#pragma unroll
      for (int r = 0; r < 4; ++r)
        vals[mi * 16 + ni * 4 + r] = (float)acc[mi][ni][r] * alpha;
  fwht64(vals);
#pragma unroll
  for (int k = 0; k < 6; ++k) {
    const int mask = 1 << k;
    const int bit = (l >> k) & 1;
#pragma unroll
    for (int i = 0; i < 64; ++i) {
      float p = __shfl_xor(vals[i], mask, 64);
      vals[i] = bit ? (p - vals[i]) : (vals[i] + p);
    }
  }
#pragma unroll
  for (int mi = 0; mi < 4; ++mi)
#pragma unroll
    for (int ni = 0; ni < 4; ++ni)
#pragma unroll
      for (int r = 0; r < 4; ++r) {
        int row = m0 + mw + mi * 16 + quad * 4 + r;
        int col = n0 + nw + ni * 16 + l15;
        C[(size_t)row * Fd + col] = bf16_rne(vals[mi * 16 + ni * 4 + r]);
      }
}

// ---------------- Output pass Ch: H64 over col-high bits, per-row, bf16 in-place ----
__global__ __launch_bounds__(256) void colhigh_fwht(u16* __restrict__ yr) {
  __shared__ u16 sh[4 * 4096];   // 32768 B = 2048 uint4 -> 8 iters of 256 threads
  const int t = threadIdx.x;
  const size_t row0 = (size_t)blockIdx.x * 4;
  uint4* shv = (uint4*)sh;
  const uint4* g = (const uint4*)(yr + row0 * 4096);
#pragma unroll
  for (int i = 0; i < 8; ++i) shv[t + 256 * i] = g[t + 256 * i];
  __syncthreads();
  const int grp = t >> 6, cl = t & 63;
  const u16* shr = sh + grp * 4096;
  float v[64];
#pragma unroll
  for (int ch = 0; ch < 64; ++ch)
    v[ch] = __uint_as_float(((u32)shr[ch * 64 + cl]) << 16);
  fwht64(v);
  __syncthreads();
  u16* shw = sh + grp * 4096;
#pragma unroll
  for (int ch = 0; ch < 64; ++ch)
    shw[ch * 64 + cl] = bf16_rne(v[ch]);
  __syncthreads();
  uint4* go = (uint4*)(yr + row0 * 4096);
#pragma unroll
  for (int i = 0; i < 8; ++i) go[t + 256 * i] = shv[t + 256 * i];
}

// ---- Output pass Rh (LAST): H64 over stride-64 rows, +bias, f32 out ----
// LDS-staged loads (G13): uint4 global reads instead of scalar u16.
__global__ __launch_bounds__(256) void rowhigh_last(const u16* __restrict__ in,
                                                    float* __restrict__ outf,
                                                    const float* __restrict__ bias) {
  __shared__ u16 tile[64 * 264];   // 64 rows x 256 cols, +8 u16 pad per row
  const int t = threadIdx.x;
  const int c0 = blockIdx.x * 256;          // col chunk base (grid.x = 16)
  const int base = blockIdx.y;              // 0..63
#pragma unroll
  for (int i = 0; i < 8; ++i) {
    int idx = t + 256 * i;                  // 0..2047
    int r = idx >> 5, u = idx & 31;
    uint4 d = *(const uint4*)(in + (size_t)(base + r * 64) * 4096 + c0 + u * 8);
    *(uint4*)(&tile[r * 264 + u * 8]) = d;
  }
  __syncthreads();
  float v[64];
#pragma unroll
  for (int r = 0; r < 64; ++r) v[r] = bf16_f32(tile[r * 264 + t]);
  fwht64(v);
  const int c = c0 + t;
  float b0 = bias[c];
#pragma unroll
  for (int r = 0; r < 64; ++r)
    outf[(size_t)(base + r * 64) * 4096 + c] = v[r] + b0;
}

// ---------------- Launch ----------------
extern "C" void kernel_launch(void* const* d_in, const int* in_sizes, int n_in,
                              void* d_out, int out_size, void* d_ws, size_t ws_size,
                              hipStream_t stream) {
  (void)in_sizes; (void)n_in; (void)out_size; (void)ws_size;
  const float* x       = (const float*)d_in[0];  // [4096,2048]
  const float* w       = (const float*)d_in[1];  // [2048,4096]
  const float* bias    = (const float*)d_in[2];  // [4096]
  const float* noise_x = (const float*)d_in[5];  // [4096,2048]
  const float* noise_w = (const float*)d_in[6];  // [2048,4096]
  char* ws = (char*)d_ws;
  char* qx   = (char*)(ws + OFF_QX);
  char* qwT  = (char*)(ws + OFF_QWT);
  u16*  X1h  = (u16*) (ws + OFF_X1B);
  u32*  W1b  = (u32*) (ws + OFF_W1B);
  u16*  yr   = (u16*) (ws + OFF_YR);
  u32*  scal = (u32*) (ws + OFF_SCAL);
  float* out = (float*)d_out;

  // x rotation: H2 @ x (2 stages, bf16 intermediate); stage1 also zeroes scal
  xcol_s1<<<dim3(8, 64), dim3(256), 0, stream>>>(x, X1h, scal);
  xcol_s2<<<dim3(8, 64), dim3(256), 0, stream>>>(X1h, scal + 0);
  // w rotation: w @ H1 (row FWHT, bf16 out) + max
  roww_fwht<<<dim3(Kd), dim3(256), 0, stream>>>(w, W1b, scal + 1);
  // stochastic int8 quantization
  quant_x_i8<<<dim3(4096), dim3(256), 0, stream>>>(
      (const uint4*)X1h, (const float4*)noise_x, (uint2*)qx, scal);
  quant_w_t_i8<<<dim3(Kd / 64, Fd / 64), dim3(256), 0, stream>>>(
      W1b, (const float2*)noise_w, qwT, scal);
  // core i8 GEMM (2-phase dbuf, GM=8) -> yr bf16 + fused Rl/Cl rotation
  gemm_i8<<<dim3((Bd / 128) * (Fd / 128)), dim3(256), 0, stream>>>(qx, qwT, yr, scal);
  // remaining output stages: col-high, then row-high (+bias, f32)
  colhigh_fwht<<<dim3(Bd / 4), dim3(256), 0, stream>>>(yr);
  rowhigh_last<<<dim3(16, 64), dim3(256), 0, stream>>>(yr, out, bias);
}

// Round 10
// 334.142 us; speedup vs baseline: 1.0633x; 1.0633x over previous
//
#include <hip/hip_runtime.h>
#include <stdint.h>

typedef unsigned short u16;
typedef unsigned int   u32;
typedef int v4i __attribute__((ext_vector_type(4)));

static constexpr int Bd = 4096;   // batch
static constexpr int Kd = 2048;   // in-features (GEMM K)
static constexpr int Fd = 4096;   // out-features

// Workspace (bytes). yr aliases X1B+W1B (dead before GEMM writes).
// wmax scratch (2048 u32 = 8 KB) lives in the FIRST 8 KB of the QWT region:
// written in K1 (prep_xw), read in K2 (xcol_s2), overwritten in K3 (quant) --
// strictly stream-ordered, no conflict.
static constexpr size_t OFF_QX   = 0;          // i8 [4096*2048]              (8 MB)
static constexpr size_t OFF_QWT  = 8388608;    // i8 [4096*2048] transposed   (8 MB)
static constexpr size_t OFF_X1B  = 16777216;   // u16[4096*2048] bf16         (16 MB)
static constexpr size_t OFF_W1B  = 33554432;   // u32[2048*2048] bf16 pairs   (16 MB)
static constexpr size_t OFF_YR   = 16777216;   // u16[4096*4096] aliases X1B/W1B (32 MB)
static constexpr size_t OFF_SCAL = 83886080;   // 2x u32 (max|X1|, max|W1| float bits)

// ---------------- FWHT helpers ----------------
__device__ __forceinline__ void fwht16(float* v) {
#pragma unroll
  for (int b = 1; b < 16; b <<= 1) {
#pragma unroll
    for (int i = 0; i < 16; ++i) {
      if (!(i & b)) { float a = v[i]; float c = v[i | b]; v[i] = a + c; v[i | b] = a - c; }
    }
  }
}
__device__ __forceinline__ void fwht64(float* v) {
#pragma unroll
  for (int b = 1; b < 64; b <<= 1) {
#pragma unroll
    for (int i = 0; i < 64; ++i) {
      if (!(i & b)) { float a = v[i]; float c = v[i | b]; v[i] = a + c; v[i | b] = a - c; }
    }
  }
}

// ---------------- bf16 pack/unpack ----------------
__device__ __forceinline__ void unpack2(u32 u, float& a, float& b) {
  a = __uint_as_float(u << 16);
  b = __uint_as_float(u & 0xffff0000u);
}
__device__ __forceinline__ float bf16_f32(u16 h) {
  return __uint_as_float(((u32)h) << 16);
}
__device__ __forceinline__ u16 bf16_rne(float f) {
  u32 x = __float_as_uint(f);
  return (u16)(((x + 0x7fffu + ((x >> 16) & 1u)) >> 16) & 0xffffu);
}
__device__ __forceinline__ u32 pack2(float a, float b) {
  u32 x = __float_as_uint(a), y = __float_as_uint(b);
  u32 lo = ((x + 0x7fffu + ((x >> 16) & 1u)) >> 16) & 0xffffu;
  u32 hi = (y + 0x7fffu + ((y >> 16) & 1u)) & 0xffff0000u;
  return lo | hi;
}

// ---- K1: xcol_s1 || roww_fwht merged (independent paths, co-scheduled) ----
// Role by blockIdx: pid<512 -> s1 (H64 on contiguous 64-row groups of x),
// pid>=512 -> roww (full FWHT-4096 per w-row). roww writes its BLOCK max to
// wmax[row] (plain store, no init needed); global w-max is reduced in K2.
// s1-role block 0 zeroes scal[0] (only touched in K2+ -> no race).
__global__ __launch_bounds__(256) void prep_xw(const float* __restrict__ x,
                                               u16* __restrict__ X1h,
                                               const float* __restrict__ w,
                                               u32* __restrict__ W1b,
                                               u32* __restrict__ wmax,
                                               u32* __restrict__ scal) {
  __shared__ __align__(16) char ldsu[33664];   // union: s1 33280 B | roww 16912 B
  const int pid = blockIdx.x;
  const int t = threadIdx.x;
  if (pid < 512) {
    // ---------------- s1 role ----------------
    if (pid == 0 && t == 0) scal[0] = 0u;
    float4* st4 = (float4*)ldsu;
    float*  stf = (float*)ldsu;
    const int c0 = (pid & 7) * 256;            // col chunk base
    const int base = (pid >> 3) * 64;          // row group base
    const int wv = t >> 6, c4 = t & 63;
    float v[64];
#pragma unroll
    for (int h = 0; h < 2; ++h) {
      if (h) __syncthreads();                  // h=0 reads done before overwrite
#pragma unroll
      for (int i = 0; i < 8; ++i) {
        int r = 4 * i + wv;                    // 0..31, wave-uniform
        st4[r * 65 + c4] =
            *(const float4*)(x + (size_t)(base + h * 32 + r) * 2048 + c0 + c4 * 4);
      }
      __syncthreads();
#pragma unroll
      for (int r = 0; r < 32; ++r) v[h * 32 + r] = stf[r * 260 + t];
    }
    fwht64(v);
    const int c = c0 + t;
#pragma unroll
    for (int r = 0; r < 64; ++r)
      X1h[(size_t)(base + r) * 2048 + c] = bf16_rne(v[r]);
  } else {
    // ---------------- roww role ----------------
    float* s   = (float*)ldsu;                 // [4224]
    float* red = (float*)(ldsu + 16896);       // [4]
    const int bx = pid - 512;                  // w row 0..2047
    const size_t rowoff = (size_t)bx * 4096;
    float v[16];
    // stage: 1024 float4 slots (16B/lane coalesced) into padded layout
#pragma unroll
    for (int i = 0; i < 4; ++i) {
      int sl = t + 256 * i;
      float4 d = *(const float4*)(w + rowoff + sl * 4);
      int ep = sl * 4 + ((sl * 4) >> 5);
      s[ep + 0] = d.x; s[ep + 1] = d.y; s[ep + 2] = d.z; s[ep + 3] = d.w;
    }
    __syncthreads();
#pragma unroll
    for (int j = 0; j < 16; ++j) { int e = (j << 8) | t; v[j] = s[e + (e >> 5)]; }
    fwht16(v);
#pragma unroll
    for (int j = 0; j < 16; ++j) { int e = (j << 8) | t; s[e + (e >> 5)] = v[j]; }
    __syncthreads();
#pragma unroll
    for (int j = 0; j < 16; ++j) { int e = ((t >> 4) << 8) | (j << 4) | (t & 15); v[j] = s[e + (e >> 5)]; }
    fwht16(v);
#pragma unroll
    for (int j = 0; j < 16; ++j) { int e = ((t >> 4) << 8) | (j << 4) | (t & 15); s[e + (e >> 5)] = v[j]; }
    __syncthreads();
#pragma unroll
    for (int j = 0; j < 16; ++j) { int e = (t << 4) | j; v[j] = s[e + (e >> 5)]; }
    fwht16(v);
    uint4 o0, o1;
    o0.x = pack2(v[0], v[1]);   o0.y = pack2(v[2], v[3]);
    o0.z = pack2(v[4], v[5]);   o0.w = pack2(v[6], v[7]);
    o1.x = pack2(v[8], v[9]);   o1.y = pack2(v[10], v[11]);
    o1.z = pack2(v[12], v[13]); o1.w = pack2(v[14], v[15]);
    uint4* op = (uint4*)(W1b + (size_t)bx * 2048 + t * 8);
    op[0] = o0; op[1] = o1;
    float m = 0.f;
#pragma unroll
    for (int j = 0; j < 16; ++j) m = fmaxf(m, fabsf(v[j]));
#pragma unroll
    for (int off = 32; off > 0; off >>= 1) m = fmaxf(m, __shfl_down(m, off));
    if ((t & 63) == 0) red[t >> 6] = m;
    __syncthreads();
    if (t == 0) {
      m = fmaxf(fmaxf(red[0], red[1]), fmaxf(red[2], red[3]));
      wmax[bx] = __float_as_uint(m);           // per-block max, reduced in K2
    }
  }
}

// ---- K2: x-path stage 2 (H64 stride-64, in-place bf16, + x-max) -------------
// Block (0,0) additionally reduces the 2048 w block-maxima into scal[1]
// (plain store; K2 runs strictly after K1, before K3).
__global__ __launch_bounds__(256) void xcol_s2(u16* __restrict__ X1h,
                                               u32* __restrict__ scal,
                                               const u32* __restrict__ wmax) {
  __shared__ u16 tile[64 * 264];   // row stride 264 u16 (+8 pad) -> spread banks
  __shared__ float red[4];
  const int t = threadIdx.x;
  const int c0 = blockIdx.x * 256;           // col chunk base (grid.x = 8)
  const int base = blockIdx.y;               // 0..63
#pragma unroll
  for (int i = 0; i < 8; ++i) {
    int idx = t + 256 * i;                   // 0..2047
    int r = idx >> 5, u = idx & 31;
    uint4 d = *(const uint4*)(X1h + (size_t)(base + r * 64) * 2048 + c0 + u * 8);
    *(uint4*)(&tile[r * 264 + u * 8]) = d;
  }
  __syncthreads();
  float v[64];
#pragma unroll
  for (int r = 0; r < 64; ++r) v[r] = bf16_f32(tile[r * 264 + t]);
  fwht64(v);
  float m = 0.f;
  const int c = c0 + t;
#pragma unroll
  for (int r = 0; r < 64; ++r) {
    X1h[(size_t)(base + r * 64) * 2048 + c] = bf16_rne(v[r]);
    m = fmaxf(m, fabsf(v[r]));
  }
#pragma unroll
  for (int off = 32; off > 0; off >>= 1) m = fmaxf(m, __shfl_down(m, off));
  if ((t & 63) == 0) red[t >> 6] = m;
  __syncthreads();
  if (t == 0) {
    m = fmaxf(fmaxf(red[0], red[1]), fmaxf(red[2], red[3]));
    atomicMax(scal, __float_as_uint(m));
  }
  // ---- w-max reduction (block (0,0) only) ----
  if (blockIdx.x == 0 && blockIdx.y == 0) {
    __syncthreads();                         // red[] reuse
    float wm = 0.f;
#pragma unroll
    for (int i = 0; i < 8; ++i) wm = fmaxf(wm, __uint_as_float(wmax[t + 256 * i]));
#pragma unroll
    for (int off = 32; off > 0; off >>= 1) wm = fmaxf(wm, __shfl_down(wm, off));
    if ((t & 63) == 0) red[t >> 6] = wm;
    __syncthreads();
    if (t == 0)
      scal[1] = __float_as_uint(fmaxf(fmaxf(red[0], red[1]), fmaxf(red[2], red[3])));
  }
}

// ---------------- Stochastic quantization ----------------
__device__ __forceinline__ float quant1(float X1, float nz, float s) {
  float xr = X1 * 0.015625f;         // /64, exact
  float xs = xr / s;
  float f  = floorf(xs);
  float q  = f + ((nz < (xs - f)) ? 1.0f : 0.0f);
  return fminf(fmaxf(q, -127.0f), 127.0f);
}
__device__ __forceinline__ u32 pk4(float a, float b, float c, float d) {
  return ((u32)(unsigned char)(char)(int)a)        |
         (((u32)(unsigned char)(char)(int)b) << 8) |
         (((u32)(unsigned char)(char)(int)c) << 16)|
         (((u32)(unsigned char)(char)(int)d) << 24);
}

// ---- K3: quant_x || quant_w_t merged (both read scal set by K1/K2) ----------
__global__ __launch_bounds__(256) void quant_xw(const uint4* __restrict__ X1b,
                                                const float4* __restrict__ nzx,
                                                uint2* __restrict__ qx,
                                                const u32* __restrict__ W1b,
                                                const float2* __restrict__ nzw,
                                                char* __restrict__ qwT,
                                                const u32* __restrict__ scal) {
  __shared__ float tile[64][65];
  const int pid = blockIdx.x;
  const int t = threadIdx.x;
  if (pid < 4096) {
    // ---------------- quant_x role ----------------
    size_t g = (size_t)pid * 256 + t;
    float s = (__uint_as_float(scal[0]) * 0.015625f) / 127.0f;
    uint4 xv = X1b[g];
    float4 na = nzx[2 * g], nb = nzx[2 * g + 1];
    float a, b, c, d, e, f, gg, h;
    unpack2(xv.x, a, b);  unpack2(xv.y, c, d);
    unpack2(xv.z, e, f);  unpack2(xv.w, gg, h);
    u32 lo = pk4(quant1(a, na.x, s), quant1(b, na.y, s), quant1(c, na.z, s), quant1(d, na.w, s));
    u32 hi = pk4(quant1(e, nb.x, s), quant1(f, nb.y, s), quant1(gg, nb.z, s), quant1(h, nb.w, s));
    qx[g] = make_uint2(lo, hi);
  } else {
    // ---------------- quant_w (transposed) role ----------------
    const int p = pid - 4096;
    const int k0 = (p & 31) * 64;   // over K=2048 (32 blocks, fast)
    const int n0 = (p >> 5) * 64;   // over F=4096 (64 blocks)
    float s = (__uint_as_float(scal[1]) * 0.015625f) / 127.0f;
#pragma unroll
    for (int i = 0; i < 8; ++i) {
      int idx = t + 256 * i;        // 0..2047 over (k, np)
      int k = idx >> 5, np = idx & 31;
      u32 u = W1b[(size_t)(k0 + k) * 2048 + (n0 >> 1) + np];
      float2 nv = nzw[(size_t)(k0 + k) * 2048 + (n0 >> 1) + np];
      float a, b; unpack2(u, a, b);
      tile[k][2 * np]     = quant1(a, nv.x, s);
      tile[k][2 * np + 1] = quant1(b, nv.y, s);
    }
    __syncthreads();
    const int kq = t & 15, nb = t >> 4;
#pragma unroll
    for (int i = 0; i < 4; ++i) {
      int n = nb + 16 * i;
      u32 pk = pk4(tile[4 * kq + 0][n], tile[4 * kq + 1][n],
                   tile[4 * kq + 2][n], tile[4 * kq + 3][n]);
      *(u32*)(qwT + (size_t)(n0 + n) * Kd + k0 + 4 * kq) = pk;
    }
  }
}

// ---------------- GEMM (i8 MFMA) + fused Rl/Cl output-rotation epilogue -------------
// 128^2 tile + 2-phase LDS double-buffer, GM=8 panel swizzle (R7/R9: 65 us,
// reproducible). R8's XCD-region swizzle halved FETCH but ran 88 us -> closed.
__device__ __forceinline__ void async16(const void* g, void* l) {
  __builtin_amdgcn_global_load_lds((__attribute__((address_space(1))) void*)(g),
                                   (__attribute__((address_space(3))) void*)(l),
                                   16, 0, 0);
}

__global__ __launch_bounds__(256) void gemm_i8(const char* __restrict__ A,   // [4096,2048] i8
                                               const char* __restrict__ Bt,  // [4096,2048] i8
                                               u16* __restrict__ C,          // [4096,4096] bf16
                                               const u32* __restrict__ scal) {
  __shared__ __align__(16) char As[2][128 * 128];
  __shared__ __align__(16) char Bs[2][128 * 128];
  const int t = threadIdx.x;
  const int w = t >> 6, l = t & 63;
  const int l15 = l & 15, quad = l >> 4;
  const int xorr = l15 & 7;
  // gm=8 panel swizzle for L2 locality (grid = 1024 1D)
  const int GM = 8, NN = 32, grp = GM * NN;
  int pid = blockIdx.x;
  int gid = pid / grp;
  int mm = gid * GM + (pid % GM);
  int nn = (pid % grp) / GM;
  const int m0 = mm * 128, n0 = nn * 128;
  const int mw = (w & 1) * 64, nw = (w >> 1) * 64;
  v4i acc[4][4] = {};

  // XOR source swizzle so LDS ds_read_b128 spreads over banks (0 conflicts)
  const int srow_lo = l >> 3;
  const int sbg = (l & 7) ^ ((l >> 3) & 7);

  // per-thread staging addresses (row/col within tile are kt-invariant)
  const int srow = (w * 4) * 8 + srow_lo;     // rows srow, srow+8, +16, +24
  const char* ga = A  + (size_t)(m0 + srow) * Kd + sbg * 16;
  const char* gb = Bt + (size_t)(n0 + srow) * Kd + sbg * 16;

  // prologue: stage K-tile 0 into buffer 0
#pragma unroll
  for (int i = 0; i < 4; ++i) {
    async16(ga + (size_t)(i * 8) * Kd, As[0] + (w * 4 + i) * 1024);
    async16(gb + (size_t)(i * 8) * Kd, Bs[0] + (w * 4 + i) * 1024);
  }
  __syncthreads();   // drains vmcnt(0): tile 0 resident

#pragma unroll 2
  for (int kt = 0; kt < 16; ++kt) {
    const char* curA = As[kt & 1];
    const char* curB = Bs[kt & 1];
    // issue next-tile staging into the alternate buffer (flies under compute)
    if (kt + 1 < 16) {
      char* nxtA = (char*)As[(kt + 1) & 1];
      char* nxtB = (char*)Bs[(kt + 1) & 1];
      const size_t kg = (size_t)(kt + 1) * 128;
#pragma unroll
      for (int i = 0; i < 4; ++i) {
        async16(ga + (size_t)(i * 8) * Kd + kg, nxtA + (w * 4 + i) * 1024);
        async16(gb + (size_t)(i * 8) * Kd + kg, nxtB + (w * 4 + i) * 1024);
      }
      __builtin_amdgcn_sched_barrier(0);   // pin: loads issued before compute
    }
#pragma unroll
    for (int kc = 0; kc < 2; ++kc) {
      v4i av[4], bv[4];
#pragma unroll
      for (int mi = 0; mi < 4; ++mi) {
        int row = mw + mi * 16 + l15;
        av[mi] = *(const v4i*)(curA + row * 128 + (((kc * 4 + quad) ^ xorr) * 16));
      }
#pragma unroll
      for (int ni = 0; ni < 4; ++ni) {
        int row = nw + ni * 16 + l15;
        bv[ni] = *(const v4i*)(curB + row * 128 + (((kc * 4 + quad) ^ xorr) * 16));
      }
#pragma unroll
      for (int mi = 0; mi < 4; ++mi)
#pragma unroll
        for (int ni = 0; ni < 4; ++ni)
          acc[mi][ni] = __builtin_amdgcn_mfma_i32_16x16x64_i8(av[mi], bv[ni], acc[mi][ni], 0, 0, 0);
    }
    // one barrier per tile: built-in vmcnt(0) waits only the residual latency
    // not covered by the compute above; also WAR-protects the buffer swap.
    __syncthreads();
  }
  float sx = (__uint_as_float(scal[0]) * 0.015625f) / 127.0f;
  float sw = (__uint_as_float(scal[1]) * 0.015625f) / 127.0f;
  float alpha = sx * sw * (1.0f / 4096.0f);

  // ---- fused epilogue: H64 over row-low bits (Rl) and col-low bits (Cl) ----
  float vals[64];
#pragma unroll
  for (int mi = 0; mi < 4; ++mi)
#pragma unroll
    for (int ni = 0; ni < 4; ++ni)
#pragma unroll
      for (int r = 0; r < 4; ++r)
        vals[mi * 16 + ni * 4 + r] = (float)acc[mi][ni][r] * alpha;
  fwht64(vals);
#pragma unroll
  for (int k = 0; k < 6; ++k) {
    const int mask = 1 << k;
    const int bit = (l >> k) & 1;
#pragma unroll
    for (int i = 0; i < 64; ++i) {
      float p = __shfl_xor(vals[i], mask, 64);
      vals[i] = bit ? (p - vals[i]) : (vals[i] + p);
    }
  }
#pragma unroll
  for (int mi = 0; mi < 4; ++mi)
#pragma unroll
    for (int ni = 0; ni < 4; ++ni)
#pragma unroll
      for (int r = 0; r < 4; ++r) {
        int row = m0 + mw + mi * 16 + quad * 4 + r;
        int col = n0 + nw + ni * 16 + l15;
        C[(size_t)row * Fd + col] = bf16_rne(vals[mi * 16 + ni * 4 + r]);
      }
}

// ---------------- Output pass Ch: H64 over col-high bits, per-row, bf16 in-place ----
__global__ __launch_bounds__(256) void colhigh_fwht(u16* __restrict__ yr) {
  __shared__ u16 sh[4 * 4096];   // 32768 B = 2048 uint4 -> 8 iters of 256 threads
  const int t = threadIdx.x;
  const size_t row0 = (size_t)blockIdx.x * 4;
  uint4* shv = (uint4*)sh;
  const uint4* g = (const uint4*)(yr + row0 * 4096);
#pragma unroll
  for (int i = 0; i < 8; ++i) shv[t + 256 * i] = g[t + 256 * i];
  __syncthreads();
  const int grp = t >> 6, cl = t & 63;
  const u16* shr = sh + grp * 4096;
  float v[64];
#pragma unroll
  for (int ch = 0; ch < 64; ++ch)
    v[ch] = __uint_as_float(((u32)shr[ch * 64 + cl]) << 16);
  fwht64(v);
  __syncthreads();
  u16* shw = sh + grp * 4096;
#pragma unroll
  for (int ch = 0; ch < 64; ++ch)
    shw[ch * 64 + cl] = bf16_rne(v[ch]);
  __syncthreads();
  uint4* go = (uint4*)(yr + row0 * 4096);
#pragma unroll
  for (int i = 0; i < 8; ++i) go[t + 256 * i] = shv[t + 256 * i];
}

// ---- Output pass Rh (LAST): H64 over stride-64 rows, +bias, f32 out ----
// LDS-staged loads (G13): uint4 global reads instead of scalar u16.
__global__ __launch_bounds__(256) void rowhigh_last(const u16* __restrict__ in,
                                                    float* __restrict__ outf,
                                                    const float* __restrict__ bias) {
  __shared__ u16 tile[64 * 264];   // 64 rows x 256 cols, +8 u16 pad per row
  const int t = threadIdx.x;
  const int c0 = blockIdx.x * 256;          // col chunk base (grid.x = 16)
  const int base = blockIdx.y;              // 0..63
#pragma unroll
  for (int i = 0; i < 8; ++i) {
    int idx = t + 256 * i;                  // 0..2047
    int r = idx >> 5, u = idx & 31;
    uint4 d = *(const uint4*)(in + (size_t)(base + r * 64) * 4096 + c0 + u * 8);
    *(uint4*)(&tile[r * 264 + u * 8]) = d;
  }
  __syncthreads();
  float v[64];
#pragma unroll
  for (int r = 0; r < 64; ++r) v[r] = bf16_f32(tile[r * 264 + t]);
  fwht64(v);
  const int c = c0 + t;
  float b0 = bias[c];
#pragma unroll
  for (int r = 0; r < 64; ++r)
    outf[(size_t)(base + r * 64) * 4096 + c] = v[r] + b0;
}

// ---------------- Launch ----------------
extern "C" void kernel_launch(void* const* d_in, const int* in_sizes, int n_in,
                              void* d_out, int out_size, void* d_ws, size_t ws_size,
                              hipStream_t stream) {
  (void)in_sizes; (void)n_in; (void)out_size; (void)ws_size;
  const float* x       = (const float*)d_in[0];  // [4096,2048]
  const float* w       = (const float*)d_in[1];  // [2048,4096]
  const float* bias    = (const float*)d_in[2];  // [4096]
  const float* noise_x = (const float*)d_in[5];  // [4096,2048]
  const float* noise_w = (const float*)d_in[6];  // [2048,4096]
  char* ws = (char*)d_ws;
  char* qx   = (char*)(ws + OFF_QX);
  char* qwT  = (char*)(ws + OFF_QWT);
  u16*  X1h  = (u16*) (ws + OFF_X1B);
  u32*  W1b  = (u32*) (ws + OFF_W1B);
  u16*  yr   = (u16*) (ws + OFF_YR);
  u32*  scal = (u32*) (ws + OFF_SCAL);
  u32*  wmax = (u32*) (ws + OFF_QWT);            // 8 KB scratch, dead before K3
  float* out = (float*)d_out;

  // K1: x rotation stage 1 || w rotation (independent, co-scheduled)
  prep_xw<<<dim3(512 + 2048), dim3(256), 0, stream>>>(x, X1h, w, W1b, wmax, scal);
  // K2: x rotation stage 2 (+x-max) and w-max reduction
  xcol_s2<<<dim3(8, 64), dim3(256), 0, stream>>>(X1h, scal, wmax);
  // K3: stochastic int8 quantization of both operands
  quant_xw<<<dim3(4096 + 2048), dim3(256), 0, stream>>>(
      (const uint4*)X1h, (const float4*)noise_x, (uint2*)qx,
      W1b, (const float2*)noise_w, qwT, scal);
  // K4: core i8 GEMM (2-phase dbuf, GM=8) -> yr bf16 + fused Rl/Cl rotation
  gemm_i8<<<dim3((Bd / 128) * (Fd / 128)), dim3(256), 0, stream>>>(qx, qwT, yr, scal);
  // K5/K6: output stages: col-high, then row-high (+bias, f32)
  colhigh_fwht<<<dim3(Bd / 4), dim3(256), 0, stream>>>(yr);
  rowhigh_last<<<dim3(16, 64), dim3(256), 0, stream>>>(yr, out, bias);
}

// Round 11
// 325.623 us; speedup vs baseline: 1.0911x; 1.0262x over previous
//
#include <hip/hip_runtime.h>
#include <stdint.h>

typedef unsigned short u16;
typedef unsigned int   u32;
typedef int v4i __attribute__((ext_vector_type(4)));

static constexpr int Bd = 4096;   // batch
static constexpr int Kd = 2048;   // in-features (GEMM K)
static constexpr int Fd = 4096;   // out-features

// Workspace (bytes). yr aliases X1B+W1B (dead before GEMM writes).
// Max-scratch arrays live in the unused [48 MiB, 80 MiB) gap: written in K1,
// read in K2, untouched by qwT/yr -> no aliasing.
static constexpr size_t OFF_QX   = 0;          // i8 [4096*2048]              (8 MB)
static constexpr size_t OFF_QWT  = 8388608;    // i8 [4096*2048] transposed   (8 MB)
static constexpr size_t OFF_X1B  = 16777216;   // u16[4096*2048] bf16         (16 MB)
static constexpr size_t OFF_W1B  = 33554432;   // u32[2048*2048] bf16 pairs   (16 MB)
static constexpr size_t OFF_YR   = 16777216;   // u16[4096*4096] aliases X1B/W1B (32 MB)
static constexpr size_t OFF_AUX  = 50331648;   // wmax[2048] u32 + xmax[256] u32
static constexpr size_t OFF_SCAL = 83886080;   // 2x u32 (max|X1|, max|W1| float bits)

// ---------------- FWHT helpers ----------------
__device__ __forceinline__ void fwht16(float* v) {
#pragma unroll
  for (int b = 1; b < 16; b <<= 1) {
#pragma unroll
    for (int i = 0; i < 16; ++i) {
      if (!(i & b)) { float a = v[i]; float c = v[i | b]; v[i] = a + c; v[i | b] = a - c; }
    }
  }
}
__device__ __forceinline__ void fwht64(float* v) {
#pragma unroll
  for (int b = 1; b < 64; b <<= 1) {
#pragma unroll
    for (int i = 0; i < 64; ++i) {
      if (!(i & b)) { float a = v[i]; float c = v[i | b]; v[i] = a + c; v[i | b] = a - c; }
    }
  }
}

// ---------------- bf16 pack/unpack ----------------
__device__ __forceinline__ void unpack2(u32 u, float& a, float& b) {
  a = __uint_as_float(u << 16);
  b = __uint_as_float(u & 0xffff0000u);
}
__device__ __forceinline__ float bf16_f32(u16 h) {
  return __uint_as_float(((u32)h) << 16);
}
__device__ __forceinline__ u16 bf16_rne(float f) {
  u32 x = __float_as_uint(f);
  return (u16)(((x + 0x7fffu + ((x >> 16) & 1u)) >> 16) & 0xffffu);
}
__device__ __forceinline__ u32 pack2(float a, float b) {
  u32 x = __float_as_uint(a), y = __float_as_uint(b);
  u32 lo = ((x + 0x7fffu + ((x >> 16) & 1u)) >> 16) & 0xffffu;
  u32 hi = (y + 0x7fffu + ((y >> 16) & 1u)) & 0xffff0000u;
  return lo | hi;
}

// ---- K1: fat_x || roww_fwht merged ------------------------------------------
// fat_x role (pid < 256): full 4096-row x-rotation on an 8-col stripe, both H64
// stages in one kernel via a 64 KB bf16 LDS tile (bf16 between stages = same
// numerics/FP-order as the old s1->s2 pair -> bit-identical). Per-block max ->
// xmax[pid]. LDS slot = 512g + 8*(r^(g&7)) + c: both stage-A (fixed r, lanes
// vary g,c) and stage-B (fixed k, lanes vary b,c) touch 32 distinct dwords per
// access -> <=2-way (free).
// roww role (pid >= 256): FWHT-4096 per w row (unchanged); block max -> wmax.
__global__ __launch_bounds__(256) void prep_xw(const float* __restrict__ x,
                                               u16* __restrict__ X1h,
                                               const float* __restrict__ w,
                                               u32* __restrict__ W1b,
                                               u32* __restrict__ wmax,
                                               u32* __restrict__ xmax) {
  __shared__ __align__(16) char ldsu[65568];   // union: fat_x 64K+16 | roww 16912
  const int pid = blockIdx.x;
  const int t = threadIdx.x;
  if (pid < 256) {
    // ---------------- fat_x role ----------------
    u16* xl = (u16*)ldsu;                      // [4096*8] bf16, swizzled
    float* redx = (float*)(ldsu + 65536);
    // XCD-aware col mapping: same-XCD blocks (pid%8 equal) cover a contiguous
    // 256-col region -> adjacent 64B lines of x stay in one XCD L2.
    const int C0 = (pid & 7) * 256 + (pid >> 3) * 8;
    const int c = t & 7;
    // stage A: H64 on contiguous 64-row groups, f32 in -> bf16 LDS
#pragma unroll
    for (int p = 0; p < 2; ++p) {
      const int g = (t >> 3) + 32 * p;         // 0..63
      float v[64];
#pragma unroll
      for (int r = 0; r < 64; ++r)
        v[r] = x[(size_t)(64 * g + r) * 2048 + C0 + c];
      fwht64(v);
#pragma unroll
      for (int r = 0; r < 64; ++r)
        xl[512 * g + 8 * (r ^ (g & 7)) + c] = bf16_rne(v[r]);
    }
    __syncthreads();
    // stage B: H64 on stride-64 rows, bf16 LDS -> bf16 global, + max
    float m = 0.f;
#pragma unroll
    for (int p = 0; p < 2; ++p) {
      const int b = (t >> 3) + 32 * p;         // 0..63
      float v[64];
#pragma unroll
      for (int k = 0; k < 64; ++k)
        v[k] = bf16_f32(xl[512 * k + 8 * ((b ^ (k & 7))) + c]);
      fwht64(v);
#pragma unroll
      for (int k = 0; k < 64; ++k) {
        X1h[(size_t)(b + 64 * k) * 2048 + C0 + c] = bf16_rne(v[k]);
        m = fmaxf(m, fabsf(v[k]));
      }
    }
#pragma unroll
    for (int off = 32; off > 0; off >>= 1) m = fmaxf(m, __shfl_down(m, off));
    if ((t & 63) == 0) redx[t >> 6] = m;
    __syncthreads();
    if (t == 0) {
      m = fmaxf(fmaxf(redx[0], redx[1]), fmaxf(redx[2], redx[3]));
      xmax[pid] = __float_as_uint(m);
    }
  } else {
    // ---------------- roww role ----------------
    float* s   = (float*)ldsu;                 // [4224]
    float* red = (float*)(ldsu + 16896);       // [4]
    const int bx = pid - 256;                  // w row 0..2047
    const size_t rowoff = (size_t)bx * 4096;
    float v[16];
#pragma unroll
    for (int i = 0; i < 4; ++i) {
      int sl = t + 256 * i;
      float4 d = *(const float4*)(w + rowoff + sl * 4);
      int ep = sl * 4 + ((sl * 4) >> 5);
      s[ep + 0] = d.x; s[ep + 1] = d.y; s[ep + 2] = d.z; s[ep + 3] = d.w;
    }
    __syncthreads();
#pragma unroll
    for (int j = 0; j < 16; ++j) { int e = (j << 8) | t; v[j] = s[e + (e >> 5)]; }
    fwht16(v);
#pragma unroll
    for (int j = 0; j < 16; ++j) { int e = (j << 8) | t; s[e + (e >> 5)] = v[j]; }
    __syncthreads();
#pragma unroll
    for (int j = 0; j < 16; ++j) { int e = ((t >> 4) << 8) | (j << 4) | (t & 15); v[j] = s[e + (e >> 5)]; }
    fwht16(v);
#pragma unroll
    for (int j = 0; j < 16; ++j) { int e = ((t >> 4) << 8) | (j << 4) | (t & 15); s[e + (e >> 5)] = v[j]; }
    __syncthreads();
#pragma unroll
    for (int j = 0; j < 16; ++j) { int e = (t << 4) | j; v[j] = s[e + (e >> 5)]; }
    fwht16(v);
    uint4 o0, o1;
    o0.x = pack2(v[0], v[1]);   o0.y = pack2(v[2], v[3]);
    o0.z = pack2(v[4], v[5]);   o0.w = pack2(v[6], v[7]);
    o1.x = pack2(v[8], v[9]);   o1.y = pack2(v[10], v[11]);
    o1.z = pack2(v[12], v[13]); o1.w = pack2(v[14], v[15]);
    uint4* op = (uint4*)(W1b + (size_t)bx * 2048 + t * 8);
    op[0] = o0; op[1] = o1;
    float m = 0.f;
#pragma unroll
    for (int j = 0; j < 16; ++j) m = fmaxf(m, fabsf(v[j]));
#pragma unroll
    for (int off = 32; off > 0; off >>= 1) m = fmaxf(m, __shfl_down(m, off));
    if ((t & 63) == 0) red[t >> 6] = m;
    __syncthreads();
    if (t == 0) {
      m = fmaxf(fmaxf(red[0], red[1]), fmaxf(red[2], red[3]));
      wmax[bx] = __float_as_uint(m);
    }
  }
}

// ---------------- Stochastic quantization ----------------
__device__ __forceinline__ float quant1(float X1, float nz, float s) {
  float xr = X1 * 0.015625f;         // /64, exact
  float xs = xr / s;
  float f  = floorf(xs);
  float q  = f + ((nz < (xs - f)) ? 1.0f : 0.0f);
  return fminf(fmaxf(q, -127.0f), 127.0f);
}
__device__ __forceinline__ u32 pk4(float a, float b, float c, float d) {
  return ((u32)(unsigned char)(char)(int)a)        |
         (((u32)(unsigned char)(char)(int)b) << 8) |
         (((u32)(unsigned char)(char)(int)c) << 16)|
         (((u32)(unsigned char)(char)(int)d) << 24);
}

// ---- K2: quant_x || quant_w_t merged; each role self-reduces its max array
// (exact fmax, same bits as the old atomicMax result) and publishes scal for
// the gemm epilogue (plain stores, stream-ordered before K3).
__global__ __launch_bounds__(256) void quant_xw(const uint4* __restrict__ X1b,
                                                const float4* __restrict__ nzx,
                                                uint2* __restrict__ qx,
                                                const u32* __restrict__ W1b,
                                                const float2* __restrict__ nzw,
                                                char* __restrict__ qwT,
                                                const u32* __restrict__ xmax,
                                                const u32* __restrict__ wmax,
                                                u32* __restrict__ scal) {
  __shared__ float tile[64][65];
  __shared__ float red[4];
  const int pid = blockIdx.x;
  const int t = threadIdx.x;
  if (pid < 4096) {
    // ---------------- quant_x role ----------------
    float xm = __uint_as_float(xmax[t]);       // 256 entries, t in 0..255
#pragma unroll
    for (int off = 32; off > 0; off >>= 1) xm = fmaxf(xm, __shfl_down(xm, off));
    if ((t & 63) == 0) red[t >> 6] = xm;
    __syncthreads();
    xm = fmaxf(fmaxf(red[0], red[1]), fmaxf(red[2], red[3]));
    if (pid == 0 && t == 0) scal[0] = __float_as_uint(xm);
    float s = (xm * 0.015625f) / 127.0f;
    size_t g = (size_t)pid * 256 + t;
    uint4 xv = X1b[g];
    float4 na = nzx[2 * g], nb = nzx[2 * g + 1];
    float a, b, c, d, e, f, gg, h;
    unpack2(xv.x, a, b);  unpack2(xv.y, c, d);
    unpack2(xv.z, e, f);  unpack2(xv.w, gg, h);
    u32 lo = pk4(quant1(a, na.x, s), quant1(b, na.y, s), quant1(c, na.z, s), quant1(d, na.w, s));
    u32 hi = pk4(quant1(e, nb.x, s), quant1(f, nb.y, s), quant1(gg, nb.z, s), quant1(h, nb.w, s));
    qx[g] = make_uint2(lo, hi);
  } else {
    // ---------------- quant_w (transposed) role ----------------
    float wm = 0.f;
#pragma unroll
    for (int i = 0; i < 8; ++i) wm = fmaxf(wm, __uint_as_float(wmax[t + 256 * i]));
#pragma unroll
    for (int off = 32; off > 0; off >>= 1) wm = fmaxf(wm, __shfl_down(wm, off));
    if ((t & 63) == 0) red[t >> 6] = wm;
    __syncthreads();
    wm = fmaxf(fmaxf(red[0], red[1]), fmaxf(red[2], red[3]));
    if (pid == 4096 && t == 0) scal[1] = __float_as_uint(wm);
    float s = (wm * 0.015625f) / 127.0f;
    const int p = pid - 4096;
    const int k0 = (p & 31) * 64;   // over K=2048
    const int n0 = (p >> 5) * 64;   // over F=4096
#pragma unroll
    for (int i = 0; i < 8; ++i) {
      int idx = t + 256 * i;        // 0..2047 over (k, np)
      int k = idx >> 5, np = idx & 31;
      u32 u = W1b[(size_t)(k0 + k) * 2048 + (n0 >> 1) + np];
      float2 nv = nzw[(size_t)(k0 + k) * 2048 + (n0 >> 1) + np];
      float a, b; unpack2(u, a, b);
      tile[k][2 * np]     = quant1(a, nv.x, s);
      tile[k][2 * np + 1] = quant1(b, nv.y, s);
    }
    __syncthreads();
    const int kq = t & 15, nb = t >> 4;
#pragma unroll
    for (int i = 0; i < 4; ++i) {
      int n = nb + 16 * i;
      u32 pk = pk4(tile[4 * kq + 0][n], tile[4 * kq + 1][n],
                   tile[4 * kq + 2][n], tile[4 * kq + 3][n]);
      *(u32*)(qwT + (size_t)(n0 + n) * Kd + k0 + 4 * kq) = pk;
    }
  }
}

// ---------------- GEMM (i8 MFMA) + fused Rl/Cl output-rotation epilogue -------------
// 128^2 tile + 2-phase LDS double-buffer, GM=8 panel swizzle (R7/R9: 65 us;
// R6/R10 showed an environmental slow mode ~88 us with identical counters).
__device__ __forceinline__ void async16(const void* g, void* l) {
  __builtin_amdgcn_global_load_lds((__attribute__((address_space(1))) void*)(g),
                                   (__attribute__((address_space(3))) void*)(l),
                                   16, 0, 0);
}

__global__ __launch_bounds__(256) void gemm_i8(const char* __restrict__ A,   // [4096,2048] i8
                                               const char* __restrict__ Bt,  // [4096,2048] i8
                                               u16* __restrict__ C,          // [4096,4096] bf16
                                               const u32* __restrict__ scal) {
  __shared__ __align__(16) char As[2][128 * 128];
  __shared__ __align__(16) char Bs[2][128 * 128];
  const int t = threadIdx.x;
  const int w = t >> 6, l = t & 63;
  const int l15 = l & 15, quad = l >> 4;
  const int xorr = l15 & 7;
  // gm=8 panel swizzle for L2 locality (grid = 1024 1D)
  const int GM = 8, NN = 32, grp = GM * NN;
  int pid = blockIdx.x;
  int gid = pid / grp;
  int mm = gid * GM + (pid % GM);
  int nn = (pid % grp) / GM;
  const int m0 = mm * 128, n0 = nn * 128;
  const int mw = (w & 1) * 64, nw = (w >> 1) * 64;
  v4i acc[4][4] = {};

  // XOR source swizzle so LDS ds_read_b128 spreads over banks (0 conflicts)
  const int srow_lo = l >> 3;
  const int sbg = (l & 7) ^ ((l >> 3) & 7);

  // per-thread staging addresses (row/col within tile are kt-invariant)
  const int srow = (w * 4) * 8 + srow_lo;     // rows srow, srow+8, +16, +24
  const char* ga = A  + (size_t)(m0 + srow) * Kd + sbg * 16;
  const char* gb = Bt + (size_t)(n0 + srow) * Kd + sbg * 16;

  // prologue: stage K-tile 0 into buffer 0
#pragma unroll
  for (int i = 0; i < 4; ++i) {
    async16(ga + (size_t)(i * 8) * Kd, As[0] + (w * 4 + i) * 1024);
    async16(gb + (size_t)(i * 8) * Kd, Bs[0] + (w * 4 + i) * 1024);
  }
  __syncthreads();   // drains vmcnt(0): tile 0 resident

#pragma unroll 2
  for (int kt = 0; kt < 16; ++kt) {
    const char* curA = As[kt & 1];
    const char* curB = Bs[kt & 1];
    // issue next-tile staging into the alternate buffer (flies under compute)
    if (kt + 1 < 16) {
      char* nxtA = (char*)As[(kt + 1) & 1];
      char* nxtB = (char*)Bs[(kt + 1) & 1];
      const size_t kg = (size_t)(kt + 1) * 128;
#pragma unroll
      for (int i = 0; i < 4; ++i) {
        async16(ga + (size_t)(i * 8) * Kd + kg, nxtA + (w * 4 + i) * 1024);
        async16(gb + (size_t)(i * 8) * Kd + kg, nxtB + (w * 4 + i) * 1024);
      }
      __builtin_amdgcn_sched_barrier(0);   // pin: loads issued before compute
    }
#pragma unroll
    for (int kc = 0; kc < 2; ++kc) {
      v4i av[4], bv[4];
#pragma unroll
      for (int mi = 0; mi < 4; ++mi) {
        int row = mw + mi * 16 + l15;
        av[mi] = *(const v4i*)(curA + row * 128 + (((kc * 4 + quad) ^ xorr) * 16));
      }
#pragma unroll
      for (int ni = 0; ni < 4; ++ni) {
        int row = nw + ni * 16 + l15;
        bv[ni] = *(const v4i*)(curB + row * 128 + (((kc * 4 + quad) ^ xorr) * 16));
      }
#pragma unroll
      for (int mi = 0; mi < 4; ++mi)
#pragma unroll
        for (int ni = 0; ni < 4; ++ni)
          acc[mi][ni] = __builtin_amdgcn_mfma_i32_16x16x64_i8(av[mi], bv[ni], acc[mi][ni], 0, 0, 0);
    }
    // one barrier per tile: built-in vmcnt(0) waits only the residual latency
    // not covered by the compute above; also WAR-protects the buffer swap.
    __syncthreads();
  }
  float sx = (__uint_as_float(scal[0]) * 0.015625f) / 127.0f;
  float sw = (__uint_as_float(scal[1]) * 0.015625f) / 127.0f;
  float alpha = sx * sw * (1.0f / 4096.0f);

  // ---- fused epilogue: H64 over row-low bits (Rl) and col-low bits (Cl) ----
  float vals[64];
#pragma unroll
  for (int mi = 0; mi < 4; ++mi)
#pragma unroll
    for (int ni = 0; ni < 4; ++ni)
#pragma unroll
      for (int r = 0; r < 4; ++r)
        vals[mi * 16 + ni * 4 + r] = (float)acc[mi][ni][r] * alpha;
  fwht64(vals);
#pragma unroll
  for (int k = 0; k < 6; ++k) {
    const int mask = 1 << k;
    const int bit = (l >> k) & 1;
#pragma unroll
    for (int i = 0; i < 64; ++i) {
      float p = __shfl_xor(vals[i], mask, 64);
      vals[i] = bit ? (p - vals[i]) : (vals[i] + p);
    }
  }
#pragma unroll
  for (int mi = 0; mi < 4; ++mi)
#pragma unroll
    for (int ni = 0; ni < 4; ++ni)
#pragma unroll
      for (int r = 0; r < 4; ++r) {
        int row = m0 + mw + mi * 16 + quad * 4 + r;
        int col = n0 + nw + ni * 16 + l15;
        C[(size_t)row * Fd + col] = bf16_rne(vals[mi * 16 + ni * 4 + r]);
      }
}

// ---------------- Output pass Ch: H64 over col-high bits, per-row, bf16 in-place ----
__global__ __launch_bounds__(256) void colhigh_fwht(u16* __restrict__ yr) {
  __shared__ u16 sh[4 * 4096];   // 32768 B = 2048 uint4 -> 8 iters of 256 threads
  const int t = threadIdx.x;
  const size_t row0 = (size_t)blockIdx.x * 4;
  uint4* shv = (uint4*)sh;
  const uint4* g = (const uint4*)(yr + row0 * 4096);
#pragma unroll
  for (int i = 0; i < 8; ++i) shv[t + 256 * i] = g[t + 256 * i];
  __syncthreads();
  const int grp = t >> 6, cl = t & 63;
  const u16* shr = sh + grp * 4096;
  float v[64];
#pragma unroll
  for (int ch = 0; ch < 64; ++ch)
    v[ch] = __uint_as_float(((u32)shr[ch * 64 + cl]) << 16);
  fwht64(v);
  __syncthreads();
  u16* shw = sh + grp * 4096;
#pragma unroll
  for (int ch = 0; ch < 64; ++ch)
    shw[ch * 64 + cl] = bf16_rne(v[ch]);
  __syncthreads();
  uint4* go = (uint4*)(yr + row0 * 4096);
#pragma unroll
  for (int i = 0; i < 8; ++i) go[t + 256 * i] = shv[t + 256 * i];
}

// ---- Output pass Rh (LAST): H64 over stride-64 rows, +bias, f32 out ----
// LDS-staged loads (G13): uint4 global reads instead of scalar u16.
__global__ __launch_bounds__(256) void rowhigh_last(const u16* __restrict__ in,
                                                    float* __restrict__ outf,
                                                    const float* __restrict__ bias) {
  __shared__ u16 tile[64 * 264];   // 64 rows x 256 cols, +8 u16 pad per row
  const int t = threadIdx.x;
  const int c0 = blockIdx.x * 256;          // col chunk base (grid.x = 16)
  const int base = blockIdx.y;              // 0..63
#pragma unroll
  for (int i = 0; i < 8; ++i) {
    int idx = t + 256 * i;                  // 0..2047
    int r = idx >> 5, u = idx & 31;
    uint4 d = *(const uint4*)(in + (size_t)(base + r * 64) * 4096 + c0 + u * 8);
    *(uint4*)(&tile[r * 264 + u * 8]) = d;
  }
  __syncthreads();
  float v[64];
#pragma unroll
  for (int r = 0; r < 64; ++r) v[r] = bf16_f32(tile[r * 264 + t]);
  fwht64(v);
  const int c = c0 + t;
  float b0 = bias[c];
#pragma unroll
  for (int r = 0; r < 64; ++r)
    outf[(size_t)(base + r * 64) * 4096 + c] = v[r] + b0;
}

// ---------------- Launch ----------------
extern "C" void kernel_launch(void* const* d_in, const int* in_sizes, int n_in,
                              void* d_out, int out_size, void* d_ws, size_t ws_size,
                              hipStream_t stream) {
  (void)in_sizes; (void)n_in; (void)out_size; (void)ws_size;
  const float* x       = (const float*)d_in[0];  // [4096,2048]
  const float* w       = (const float*)d_in[1];  // [2048,4096]
  const float* bias    = (const float*)d_in[2];  // [4096]
  const float* noise_x = (const float*)d_in[5];  // [4096,2048]
  const float* noise_w = (const float*)d_in[6];  // [2048,4096]
  char* ws = (char*)d_ws;
  char* qx   = (char*)(ws + OFF_QX);
  char* qwT  = (char*)(ws + OFF_QWT);
  u16*  X1h  = (u16*) (ws + OFF_X1B);
  u32*  W1b  = (u32*) (ws + OFF_W1B);
  u16*  yr   = (u16*) (ws + OFF_YR);
  u32*  wmax = (u32*) (ws + OFF_AUX);            // [2048]
  u32*  xmax = (u32*) (ws + OFF_AUX + 8192);     // [256]
  u32*  scal = (u32*) (ws + OFF_SCAL);
  float* out = (float*)d_out;

  // K1: full x rotation (both H64 stages, LDS-internal) || w rotation
  prep_xw<<<dim3(256 + 2048), dim3(256), 0, stream>>>(x, X1h, w, W1b, wmax, xmax);
  // K2: stochastic int8 quantization of both operands (self-reduced maxima)
  quant_xw<<<dim3(4096 + 2048), dim3(256), 0, stream>>>(
      (const uint4*)X1h, (const float4*)noise_x, (uint2*)qx,
      W1b, (const float2*)noise_w, qwT, xmax, wmax, scal);
  // K3: core i8 GEMM (2-phase dbuf, GM=8) -> yr bf16 + fused Rl/Cl rotation
  gemm_i8<<<dim3((Bd / 128) * (Fd / 128)), dim3(256), 0, stream>>>(qx, qwT, yr, scal);
  // K4/K5: output stages: col-high, then row-high (+bias, f32)
  colhigh_fwht<<<dim3(Bd / 4), dim3(256), 0, stream>>>(yr);
  rowhigh_last<<<dim3(16, 64), dim3(256), 0, stream>>>(yr, out, bias);
}